// Round 10
// baseline (251.222 us; speedup 1.0000x reference)
//
#include <hip/hip_runtime.h>
#include <math.h>

#define B_   4
#define NQ_  300
#define DIM_ 256
#define H_   8
#define HD_  32
#define N_   4096

typedef _Float16 f16;
typedef f16   f16x8 __attribute__((ext_vector_type(8)));
typedef f16   f16x4 __attribute__((ext_vector_type(4)));
typedef float f32x4 __attribute__((ext_vector_type(4)));

#define L2E 1.44269504f

// ---------------------------------------------------------------------------
// Prep: z<4 -> WT[z][n][k] = W_z[k][n] * (z==0 ? qscale : 1), f16.
//       z==4 -> maskf[b][n] = -100*log2e*mask[b][n], f32.
// ---------------------------------------------------------------------------
__global__ __launch_bounds__(256) void prep_wt(
    const float* __restrict__ Wq, const float* __restrict__ Wk,
    const float* __restrict__ Wv, const float* __restrict__ Wp,
    const int* __restrict__ mask, f16* __restrict__ WT,
    float* __restrict__ maskf, float qscale)
{
  const int z = blockIdx.z;
  if (z == 4) {
    const int flat = blockIdx.y * 4 + blockIdx.x;
    const int idx = flat * 1024 + threadIdx.x * 4;
    int4 mm = *(const int4*)(mask + idx);
    float4 o;
    o.x = -100.f * L2E * (float)mm.x;
    o.y = -100.f * L2E * (float)mm.y;
    o.z = -100.f * L2E * (float)mm.z;
    o.w = -100.f * L2E * (float)mm.w;
    *(float4*)(maskf + idx) = o;
    return;
  }
  __shared__ float t[64][65];
  const float* W = z == 0 ? Wq : z == 1 ? Wk : z == 2 ? Wv : Wp;
  const float s = z == 0 ? qscale : 1.0f;
  f16* O = WT + (size_t)z * 65536;
  const int k0 = blockIdx.y * 64, n0 = blockIdx.x * 64;
  const int r = threadIdx.x >> 2, c0 = (threadIdx.x & 3) * 16;
#pragma unroll
  for (int c = 0; c < 16; c += 4) {
    float4 v = *(const float4*)(W + (size_t)(k0 + r) * 256 + n0 + c0 + c);
    t[r][c0 + c] = v.x; t[r][c0 + c + 1] = v.y;
    t[r][c0 + c + 2] = v.z; t[r][c0 + c + 3] = v.w;
  }
  __syncthreads();
  f16* orow = O + (size_t)(n0 + r) * 256 + k0 + c0;
#pragma unroll
  for (int c = 0; c < 16; c += 4) {
    f16x4 p;
    p[0] = (f16)(t[c0 + c + 0][r] * s);
    p[1] = (f16)(t[c0 + c + 1][r] * s);
    p[2] = (f16)(t[c0 + c + 2][r] * s);
    p[3] = (f16)(t[c0 + c + 3][r] * s);
    *(f16x4*)(orow + c) = p;
  }
}

// ---------------------------------------------------------------------------
// MFMA GEMM body, 128(m) x 64(n) tile, K=256. WT is [n][k] f16.
// Wave wv: rows wv*32..+32 (two 16-row MFMA tiles) x all 64 n -> 8 MFMA/step.
// mode 0: fp32 row-major out; 1: f16 row-major;
// mode 2: f16 [b][c=n][nk=m&4095] via LDS transpose (64B coalesced stores).
// ---------------------------------------------------------------------------
__device__ __forceinline__ void gemm_body(
    const void* __restrict__ Ain, const f16* __restrict__ WT,
    const float* __restrict__ bias, void* __restrict__ C,
    int M, int a_f16, int mode, int bm, int bn, int tid)
{
  __shared__ f16 As[128][40];
  __shared__ f16 Bs[64][40];
  __shared__ f16 Ts[64][132];
  const int lane = tid & 63;
  const int wv = tid >> 6;
  const int l15 = lane & 15, g = lane >> 4;

  f32x4 acc[2][4];
#pragma unroll
  for (int mt = 0; mt < 2; ++mt)
#pragma unroll
    for (int nt = 0; nt < 4; ++nt) acc[mt][nt] = (f32x4){0.f, 0.f, 0.f, 0.f};

  for (int k0 = 0; k0 < 256; k0 += 32) {
#pragma unroll
    for (int i = 0; i < 2; ++i) {
      const int c = tid + i * 256;
      const int row = c >> 2, k8 = (c & 3) * 8;
      const int gm = bm + row;
      f16x8 av;
      if (gm < M) {
        if (a_f16) {
          av = *(const f16x8*)((const f16*)Ain + (size_t)gm * 256 + k0 + k8);
        } else {
          const float* ap = (const float*)Ain + (size_t)gm * 256 + k0 + k8;
          float4 a0 = *(const float4*)ap;
          float4 a1 = *(const float4*)(ap + 4);
          av[0] = (f16)a0.x; av[1] = (f16)a0.y; av[2] = (f16)a0.z; av[3] = (f16)a0.w;
          av[4] = (f16)a1.x; av[5] = (f16)a1.y; av[6] = (f16)a1.z; av[7] = (f16)a1.w;
        }
      } else {
#pragma unroll
        for (int j = 0; j < 8; ++j) av[j] = (f16)0.f;
      }
      *(f16x8*)&As[row][k8] = av;
    }
    {
      const int n = tid >> 2, k8 = (tid & 3) * 8;
      *(f16x8*)&Bs[n][k8] = *(const f16x8*)(WT + (size_t)(bn + n) * 256 + k0 + k8);
    }
    __syncthreads();
    const f16x8 af0 = *(const f16x8*)&As[wv * 32 + l15][g * 8];
    const f16x8 af1 = *(const f16x8*)&As[wv * 32 + 16 + l15][g * 8];
#pragma unroll
    for (int nt = 0; nt < 4; ++nt) {
      const f16x8 bf = *(const f16x8*)&Bs[nt * 16 + l15][g * 8];
      acc[0][nt] = __builtin_amdgcn_mfma_f32_16x16x32_f16(af0, bf, acc[0][nt], 0, 0, 0);
      acc[1][nt] = __builtin_amdgcn_mfma_f32_16x16x32_f16(af1, bf, acc[1][nt], 0, 0, 0);
    }
    __syncthreads();
  }

  if (mode == 2) {
#pragma unroll
    for (int nt = 0; nt < 4; ++nt) {
      const float bv = bias[bn + nt * 16 + l15];
#pragma unroll
      for (int mt = 0; mt < 2; ++mt)
#pragma unroll
        for (int r = 0; r < 4; ++r)
          Ts[nt * 16 + l15][wv * 32 + mt * 16 + g * 4 + r] = (f16)(acc[mt][nt][r] + bv);
    }
    __syncthreads();
    const int n = tid >> 2, mc = (tid & 3) * 32;
    const int bb = bm >> 12, nk0 = bm & 4095;
    f16* dst = (f16*)C + (size_t)bb * (256 * 4096) +
               (size_t)(bn + n) * 4096 + nk0 + mc;
#pragma unroll
    for (int j = 0; j < 4; ++j)
      *(f16x8*)(dst + j * 8) = *(const f16x8*)&Ts[n][mc + j * 8];
  } else {
#pragma unroll
    for (int nt = 0; nt < 4; ++nt) {
      const int n = bn + nt * 16 + l15;
      const float bv = bias[n];
#pragma unroll
      for (int mt = 0; mt < 2; ++mt)
#pragma unroll
      for (int r = 0; r < 4; ++r) {
        const int m = bm + wv * 32 + mt * 16 + g * 4 + r;
        if (m >= M) continue;
        const float v = acc[mt][nt][r] + bv;
        if (mode == 0) ((float*)C)[(size_t)m * 256 + n] = v;
        else           ((f16*)C)[(size_t)m * 256 + n] = (f16)v;
      }
    }
  }
}

// z=0: Q (M=1200, blocks beyond early-out), z=1: K, z=2: V.
__global__ __launch_bounds__(256) void proj_qkv(
    const float* __restrict__ query, const float* __restrict__ kin,
    const float* __restrict__ vin, const f16* __restrict__ WT,
    const float* __restrict__ bq, const float* __restrict__ bk,
    const float* __restrict__ bv, f16* __restrict__ Qf,
    f16* __restrict__ Kf, f16* __restrict__ Vtf)
{
  const int z = blockIdx.z;
  const int bm = blockIdx.y * 128, bn = blockIdx.x * 64;
  if (z == 0) {
    if (bm >= B_ * NQ_) return;
    gemm_body(query, WT, bq, Qf, B_ * NQ_, 0, 1, bm, bn, threadIdx.x);
  } else if (z == 1) {
    gemm_body(kin, WT + 65536, bk, Kf, B_ * N_, 0, 1, bm, bn, threadIdx.x);
  } else {
    gemm_body(vin, WT + 2 * 65536, bv, Vtf, B_ * N_, 0, 2, bm, bn, threadIdx.x);
  }
}

__global__ __launch_bounds__(256) void gemm_out(
    const f16* __restrict__ X, const f16* __restrict__ WT,
    const float* __restrict__ bp, float* __restrict__ out)
{
  gemm_body(X, WT + 3 * 65536, bp, out, B_ * NQ_, 1, 0,
            blockIdx.y * 128, blockIdx.x * 64, threadIdx.x);
}

// ---------------------------------------------------------------------------
// RPE MLP, fp32 (rpe ~±1500; must not round). Output transposed to
// [b][h][q][j], pre-scaled by log2e, for coalesced float4 staging in attn.
// ---------------------------------------------------------------------------
__global__ __launch_bounds__(256) void rpe_kernel(
    const float* __restrict__ refpts,
    const float* __restrict__ W1x, const float* __restrict__ b1x, const float* __restrict__ W2x,
    const float* __restrict__ W1y, const float* __restrict__ b1y, const float* __restrict__ W2y,
    float* __restrict__ rpxT, float* __restrict__ rpyT)
{
  __shared__ float sRed[4][64][9];
  const int tid = threadIdx.x;
  const int lane = tid & 63;
  const int wv = __builtin_amdgcn_readfirstlane(tid >> 6);
  const int bq = blockIdx.x;
  const int axis = blockIdx.y;
  const float* W1 = axis ? W1y : W1x;
  const float* b1 = axis ? b1y : b1x;
  const float* W2 = axis ? W2y : W2x;
  float* out = axis ? rpyT : rpxT;
  const int b = bq / NQ_, q = bq % NQ_;

  const float c  = refpts[bq * 4 + axis];
  const float sz = refpts[bq * 4 + 2 + axis];
  const float pos = (lane + 0.5f) * 16.0f;
  const float d0 = c - 0.5f * sz - pos;
  const float d1 = c + 0.5f * sz - pos;
  float acc[8] = {};
  const int r0 = wv * 128;
#pragma unroll 4
  for (int i = 0; i < 128; ++i) {
    const int r = r0 + i;
    const float w10 = W1[r], w11 = W1[512 + r], bb = b1[r];
    const float hv = fmaxf(fmaf(d0, w10, fmaf(d1, w11, bb)), 0.0f);
    const float* w2r = W2 + r * 8;
#pragma unroll
    for (int hh = 0; hh < 8; ++hh) acc[hh] += hv * w2r[hh];
  }
#pragma unroll
  for (int hh = 0; hh < 8; ++hh) sRed[wv][lane][hh] = acc[hh];
  __syncthreads();
  for (int idx = tid; idx < 512; idx += 256) {
    const int hh = idx >> 6, jj = idx & 63;
    out[((size_t)(b * H_ + hh) * NQ_ + q) * 64 + jj] =
        (sRed[0][jj][hh] + sRed[1][jj][hh] + sRed[2][jj][hh] + sRed[3][jj][hh]) * L2E;
  }
}

// ---------------------------------------------------------------------------
// Two-phase exact-softmax MFMA attention.
// Block = (b,h,32q): two 16-q tiles per wave, 8 waves x 512 keys, grid 320.
// Phase 1: QK + fixup, per-LANE running max only (no cross-lane ops, no
//   rescaling — every 64-key sub-pass independent). One block-wide LDS
//   max-reduce yields the exact row max m per query.
// Phase 2: recompute QK (K is L2-hot), p = exp2(s - m) -> PV, plain l/O
//   accumulation. Merge across waves is a simple sum (shared m).
// ---------------------------------------------------------------------------
__global__ __launch_bounds__(512, 4) void attn_mfma(
    const f16* __restrict__ Qf, const f16* __restrict__ Kf,
    const f16* __restrict__ Vtf, const float* __restrict__ rpxT,
    const float* __restrict__ rpyT, const float* __restrict__ maskf,
    f16* __restrict__ X)
{
  __shared__ float srx[32][68];
  __shared__ float sry[32][68];
  __shared__ float pm[8][2][64];       // per-wave, per-qtile lane maxima
  __shared__ f16x4 mO4[7][4][64];      // O partial merge (f16)
  __shared__ float mll[7][32];         // l partial merge

  const int tid = threadIdx.x;
  const int lane = tid & 63;
  const int kh = tid >> 6;
  const int qg = blockIdx.x % 10;
  const int h  = (blockIdx.x / 10) % H_;
  const int b  = blockIdx.x / (10 * H_);
  const int q0 = qg * 32;

  {
    const int qq = tid >> 4, j4 = tid & 15;
    int qa = q0 + qq; if (qa > NQ_ - 1) qa = NQ_ - 1;
    const size_t base = ((size_t)((b * H_ + h) * NQ_ + qa)) * 64 + j4 * 4;
    *(float4*)&srx[qq][j4 * 4] = *(const float4*)(rpxT + base);
    *(float4*)&sry[qq][j4 * 4] = *(const float4*)(rpyT + base);
  }
  __syncthreads();

  const int l15 = lane & 15, g = lane >> 4;
  const int qrow0 = q0 + l15;
  const int qrow1 = q0 + 16 + l15;
  const int qa = qrow0 > NQ_ - 1 ? NQ_ - 1 : qrow0;
  const int qb = qrow1 > NQ_ - 1 ? NQ_ - 1 : qrow1;

  const f16x8 qf0 = *(const f16x8*)(Qf + (size_t)(b * NQ_ + qa) * 256 + h * 32 + g * 8);
  const f16x8 qf1 = *(const f16x8*)(Qf + (size_t)(b * NQ_ + qb) * 256 + h * 32 + g * 8);

  const f16* kb  = Kf + (size_t)b * N_ * 256 + h * 32 + g * 8;
  const f16* v0p = Vtf + (size_t)(b * 256 + h * 32 + l15) * N_ + g * 4;
  const f16* v1p = v0p + (size_t)16 * N_;
  const float* mb = maskf + b * N_;

  // ---------------- Phase 1: per-lane score max ----------------
  float cmax0 = -1e30f, cmax1 = -1e30f;
  for (int sp = 0; sp < 8; ++sp) {
    const int kbase = kh * 512 + sp * 64;
    f16x8 kf[4]; float4 m4[4];
#pragma unroll
    for (int cc = 0; cc < 4; ++cc) {
      kf[cc] = *(const f16x8*)(kb + (size_t)(kbase + cc * 16 + l15) * 256);
      m4[cc] = *(const float4*)(mb + kbase + cc * 16 + g * 4);
    }
    const float ry0 = sry[l15][kbase >> 6];
    const float ry1 = sry[16 + l15][kbase >> 6];
#pragma unroll
    for (int cc = 0; cc < 4; ++cc) {
      f32x4 S0 = __builtin_amdgcn_mfma_f32_16x16x32_f16(
          kf[cc], qf0, (f32x4){0.f, 0.f, 0.f, 0.f}, 0, 0, 0);
      f32x4 S1 = __builtin_amdgcn_mfma_f32_16x16x32_f16(
          kf[cc], qf1, (f32x4){0.f, 0.f, 0.f, 0.f}, 0, 0, 0);
      const float4 rx0 = *(const float4*)&srx[l15][cc * 16 + g * 4];
      const float4 rx1 = *(const float4*)&srx[16 + l15][cc * 16 + g * 4];
      cmax0 = fmaxf(cmax0, fmaxf(
          fmaxf(fmaf(S0[0], L2E, rx0.x + m4[cc].x + ry0),
                fmaf(S0[1], L2E, rx0.y + m4[cc].y + ry0)),
          fmaxf(fmaf(S0[2], L2E, rx0.z + m4[cc].z + ry0),
                fmaf(S0[3], L2E, rx0.w + m4[cc].w + ry0))));
      cmax1 = fmaxf(cmax1, fmaxf(
          fmaxf(fmaf(S1[0], L2E, rx1.x + m4[cc].x + ry1),
                fmaf(S1[1], L2E, rx1.y + m4[cc].y + ry1)),
          fmaxf(fmaf(S1[2], L2E, rx1.z + m4[cc].z + ry1),
                fmaf(S1[3], L2E, rx1.w + m4[cc].w + ry1))));
    }
  }
  pm[kh][0][lane] = cmax0;
  pm[kh][1][lane] = cmax1;
  __syncthreads();
  float m0 = -1e30f, m1 = -1e30f;
#pragma unroll
  for (int w = 0; w < 8; ++w)
#pragma unroll
    for (int gg = 0; gg < 4; ++gg) {
      m0 = fmaxf(m0, pm[w][0][gg * 16 + l15]);
      m1 = fmaxf(m1, pm[w][1][gg * 16 + l15]);
    }

  // ---------------- Phase 2: exp + PV ----------------
  f32x4 O00 = {0.f,0.f,0.f,0.f}, O01 = {0.f,0.f,0.f,0.f};
  f32x4 O10 = {0.f,0.f,0.f,0.f}, O11 = {0.f,0.f,0.f,0.f};
  float lacc0 = 0.f, lacc1 = 0.f;
  for (int sp = 0; sp < 8; ++sp) {
    const int kbase = kh * 512 + sp * 64;
    f16x8 kf[4]; f16x4 va[4], vb[4]; float4 m4[4];
#pragma unroll
    for (int cc = 0; cc < 4; ++cc) {
      kf[cc] = *(const f16x8*)(kb + (size_t)(kbase + cc * 16 + l15) * 256);
      va[cc] = *(const f16x4*)(v0p + kbase + cc * 16);
      vb[cc] = *(const f16x4*)(v1p + kbase + cc * 16);
      m4[cc] = *(const float4*)(mb + kbase + cc * 16 + g * 4);
    }
    const float ry0 = sry[l15][kbase >> 6] - m0;
    const float ry1 = sry[16 + l15][kbase >> 6] - m1;
#pragma unroll
    for (int cc = 0; cc < 4; ++cc) {
      f32x4 S0 = __builtin_amdgcn_mfma_f32_16x16x32_f16(
          kf[cc], qf0, (f32x4){0.f, 0.f, 0.f, 0.f}, 0, 0, 0);
      f32x4 S1 = __builtin_amdgcn_mfma_f32_16x16x32_f16(
          kf[cc], qf1, (f32x4){0.f, 0.f, 0.f, 0.f}, 0, 0, 0);
      const float4 rx0 = *(const float4*)&srx[l15][cc * 16 + g * 4];
      const float4 rx1 = *(const float4*)&srx[16 + l15][cc * 16 + g * 4];
      f16x4 pf0, pf1;
      {
        const float p0 = exp2f(fmaf(S0[0], L2E, rx0.x + m4[cc].x + ry0));
        const float p1 = exp2f(fmaf(S0[1], L2E, rx0.y + m4[cc].y + ry0));
        const float p2 = exp2f(fmaf(S0[2], L2E, rx0.z + m4[cc].z + ry0));
        const float p3 = exp2f(fmaf(S0[3], L2E, rx0.w + m4[cc].w + ry0));
        lacc0 += p0 + p1 + p2 + p3;
        pf0[0] = (f16)p0; pf0[1] = (f16)p1; pf0[2] = (f16)p2; pf0[3] = (f16)p3;
      }
      {
        const float p0 = exp2f(fmaf(S1[0], L2E, rx1.x + m4[cc].x + ry1));
        const float p1 = exp2f(fmaf(S1[1], L2E, rx1.y + m4[cc].y + ry1));
        const float p2 = exp2f(fmaf(S1[2], L2E, rx1.z + m4[cc].z + ry1));
        const float p3 = exp2f(fmaf(S1[3], L2E, rx1.w + m4[cc].w + ry1));
        lacc1 += p0 + p1 + p2 + p3;
        pf1[0] = (f16)p0; pf1[1] = (f16)p1; pf1[2] = (f16)p2; pf1[3] = (f16)p3;
      }
      O00 = __builtin_amdgcn_mfma_f32_16x16x16f16(va[cc], pf0, O00, 0, 0, 0);
      O01 = __builtin_amdgcn_mfma_f32_16x16x16f16(vb[cc], pf0, O01, 0, 0, 0);
      O10 = __builtin_amdgcn_mfma_f32_16x16x16f16(va[cc], pf1, O10, 0, 0, 0);
      O11 = __builtin_amdgcn_mfma_f32_16x16x16f16(vb[cc], pf1, O11, 0, 0, 0);
    }
  }
  lacc0 += __shfl_xor(lacc0, 16); lacc0 += __shfl_xor(lacc0, 32);
  lacc1 += __shfl_xor(lacc1, 16); lacc1 += __shfl_xor(lacc1, 32);

  if (kh > 0) {
    f16x4 t;
#pragma unroll
    for (int r = 0; r < 4; ++r) t[r] = (f16)O00[r];
    mO4[kh - 1][0][lane] = t;
#pragma unroll
    for (int r = 0; r < 4; ++r) t[r] = (f16)O01[r];
    mO4[kh - 1][1][lane] = t;
#pragma unroll
    for (int r = 0; r < 4; ++r) t[r] = (f16)O10[r];
    mO4[kh - 1][2][lane] = t;
#pragma unroll
    for (int r = 0; r < 4; ++r) t[r] = (f16)O11[r];
    mO4[kh - 1][3][lane] = t;
    if (lane < 16) {
      mll[kh - 1][lane]      = lacc0;
      mll[kh - 1][16 + lane] = lacc1;
    }
  }
  __syncthreads();
  if (kh == 0) {
    float lt0 = lacc0, lt1 = lacc1;
#pragma unroll
    for (int w = 0; w < 7; ++w) {
      lt0 += mll[w][l15];
      lt1 += mll[w][16 + l15];
#pragma unroll
      for (int r = 0; r < 4; ++r) {
        O00[r] += (float)mO4[w][0][lane][r];
        O01[r] += (float)mO4[w][1][lane][r];
        O10[r] += (float)mO4[w][2][lane][r];
        O11[r] += (float)mO4[w][3][lane][r];
      }
    }
    const float rl0 = 1.0f / lt0;
    const float rl1 = 1.0f / lt1;
    if (qrow0 < NQ_) {
      f16* xr = X + (size_t)(b * NQ_ + qrow0) * 256 + h * 32;
      f16x4 p0, p1;
#pragma unroll
      for (int r = 0; r < 4; ++r) {
        p0[r] = (f16)(O00[r] * rl0);
        p1[r] = (f16)(O01[r] * rl0);
      }
      *(f16x4*)(xr + g * 4) = p0;
      *(f16x4*)(xr + 16 + g * 4) = p1;
    }
    if (qrow1 < NQ_) {
      f16* xr = X + (size_t)(b * NQ_ + qrow1) * 256 + h * 32;
      f16x4 p0, p1;
#pragma unroll
      for (int r = 0; r < 4; ++r) {
        p0[r] = (f16)(O10[r] * rl1);
        p1[r] = (f16)(O11[r] * rl1);
      }
      *(f16x4*)(xr + g * 4) = p0;
      *(f16x4*)(xr + 16 + g * 4) = p1;
    }
  }
}

// ---------------------------------------------------------------------------
extern "C" void kernel_launch(void* const* d_in, const int* in_sizes, int n_in,
                              void* d_out, int out_size, void* d_ws, size_t ws_size,
                              hipStream_t stream)
{
  const float* query  = (const float*)d_in[0];
  const float* refpts = (const float*)d_in[1];
  const float* kin    = (const float*)d_in[2];
  const float* vin    = (const float*)d_in[3];
  const int*   mask   = (const int*)d_in[5];
  const float* Wq = (const float*)d_in[6];
  const float* bq = (const float*)d_in[7];
  const float* Wk = (const float*)d_in[8];
  const float* bk = (const float*)d_in[9];
  const float* Wv = (const float*)d_in[10];
  const float* bv = (const float*)d_in[11];
  const float* Wp = (const float*)d_in[12];
  const float* bp = (const float*)d_in[13];
  const float* W1x = (const float*)d_in[14];
  const float* b1x = (const float*)d_in[15];
  const float* W2x = (const float*)d_in[16];
  const float* W1y = (const float*)d_in[17];
  const float* b1y = (const float*)d_in[18];
  const float* W2y = (const float*)d_in[19];

  char* wsb = (char*)d_ws;
  f16*   Qf    = (f16*)(wsb);                 // 1280*256 f16
  f16*   Kf    = (f16*)(wsb + 655360);        // 4*4096*256 f16 = 8388608 B
  f16*   Vtf   = (f16*)(wsb + 9043968);       // 4*256*4096 f16 = 8388608 B
  float* rpxT  = (float*)(wsb + 17432576);    // 4*8*300*64 f32 = 2457600 B
  float* rpyT  = (float*)(wsb + 19890176);    // 2457600 B
  f16*   X     = (f16*)(wsb + 22347776);      // 1280*256 f16
  f16*   WT    = (f16*)(wsb + 23003136);      // 4*256*256 f16  = 524288 B
  float* maskf = (float*)(wsb + 23527424);    // 4*4096 f32     = 65536 B

  const float scale = 0.17677669529663687f;  // 32^-0.5

  hipLaunchKernelGGL(prep_wt, dim3(4, 4, 5), dim3(256), 0, stream,
                     Wq, Wk, Wv, Wp, mask, WT, maskf, scale);
  hipLaunchKernelGGL(rpe_kernel, dim3(B_ * NQ_, 2), dim3(256), 0, stream,
                     refpts, W1x, b1x, W2x, W1y, b1y, W2y, rpxT, rpyT);
  hipLaunchKernelGGL(proj_qkv, dim3(4, 128, 3), dim3(256), 0, stream,
                     query, kin, vin, WT, bq, bk, bv, Qf, Kf, Vtf);
  hipLaunchKernelGGL(attn_mfma, dim3(B_ * H_ * 10), dim3(512), 0, stream,
                     Qf, Kf, Vtf, rpxT, rpyT, maskf, X);
  hipLaunchKernelGGL(gemm_out, dim3(4, 10), dim3(256), 0, stream,
                     X, WT, bp, (float*)d_out);
}

// Round 11
// 226.317 us; speedup vs baseline: 1.1100x; 1.1100x over previous
//
#include <hip/hip_runtime.h>
#include <math.h>

#define B_   4
#define NQ_  300
#define DIM_ 256
#define H_   8
#define HD_  32
#define N_   4096

typedef _Float16 f16;
typedef f16   f16x8 __attribute__((ext_vector_type(8)));
typedef f16   f16x4 __attribute__((ext_vector_type(4)));
typedef float f32x4 __attribute__((ext_vector_type(4)));

#define L2E 1.44269504f

// ---------------------------------------------------------------------------
// Prep: z<4 -> WT[z][n][k] = W_z[k][n] * (z==0 ? qscale : 1), f16.
//       z==4 -> maskf[b][n] = -100*log2e*mask[b][n], f32.
// ---------------------------------------------------------------------------
__global__ __launch_bounds__(256) void prep_wt(
    const float* __restrict__ Wq, const float* __restrict__ Wk,
    const float* __restrict__ Wv, const float* __restrict__ Wp,
    const int* __restrict__ mask, f16* __restrict__ WT,
    float* __restrict__ maskf, float qscale)
{
  const int z = blockIdx.z;
  if (z == 4) {
    const int flat = blockIdx.y * 4 + blockIdx.x;
    const int idx = flat * 1024 + threadIdx.x * 4;
    int4 mm = *(const int4*)(mask + idx);
    float4 o;
    o.x = -100.f * L2E * (float)mm.x;
    o.y = -100.f * L2E * (float)mm.y;
    o.z = -100.f * L2E * (float)mm.z;
    o.w = -100.f * L2E * (float)mm.w;
    *(float4*)(maskf + idx) = o;
    return;
  }
  __shared__ float t[64][65];
  const float* W = z == 0 ? Wq : z == 1 ? Wk : z == 2 ? Wv : Wp;
  const float s = z == 0 ? qscale : 1.0f;
  f16* O = WT + (size_t)z * 65536;
  const int k0 = blockIdx.y * 64, n0 = blockIdx.x * 64;
  const int r = threadIdx.x >> 2, c0 = (threadIdx.x & 3) * 16;
#pragma unroll
  for (int c = 0; c < 16; c += 4) {
    float4 v = *(const float4*)(W + (size_t)(k0 + r) * 256 + n0 + c0 + c);
    t[r][c0 + c] = v.x; t[r][c0 + c + 1] = v.y;
    t[r][c0 + c + 2] = v.z; t[r][c0 + c + 3] = v.w;
  }
  __syncthreads();
  f16* orow = O + (size_t)(n0 + r) * 256 + k0 + c0;
#pragma unroll
  for (int c = 0; c < 16; c += 4) {
    f16x4 p;
    p[0] = (f16)(t[c0 + c + 0][r] * s);
    p[1] = (f16)(t[c0 + c + 1][r] * s);
    p[2] = (f16)(t[c0 + c + 2][r] * s);
    p[3] = (f16)(t[c0 + c + 3][r] * s);
    *(f16x4*)(orow + c) = p;
  }
}

// ---------------------------------------------------------------------------
// MFMA GEMM body, 128(m) x 64(n) tile, K=256. WT is [n][k] f16.
// ---------------------------------------------------------------------------
__device__ __forceinline__ void gemm_body(
    const void* __restrict__ Ain, const f16* __restrict__ WT,
    const float* __restrict__ bias, void* __restrict__ C,
    int M, int a_f16, int mode, int bm, int bn, int tid)
{
  __shared__ f16 As[128][40];
  __shared__ f16 Bs[64][40];
  __shared__ f16 Ts[64][132];
  const int lane = tid & 63;
  const int wv = tid >> 6;
  const int l15 = lane & 15, g = lane >> 4;

  f32x4 acc[2][4];
#pragma unroll
  for (int mt = 0; mt < 2; ++mt)
#pragma unroll
    for (int nt = 0; nt < 4; ++nt) acc[mt][nt] = (f32x4){0.f, 0.f, 0.f, 0.f};

  for (int k0 = 0; k0 < 256; k0 += 32) {
#pragma unroll
    for (int i = 0; i < 2; ++i) {
      const int c = tid + i * 256;
      const int row = c >> 2, k8 = (c & 3) * 8;
      const int gm = bm + row;
      f16x8 av;
      if (gm < M) {
        if (a_f16) {
          av = *(const f16x8*)((const f16*)Ain + (size_t)gm * 256 + k0 + k8);
        } else {
          const float* ap = (const float*)Ain + (size_t)gm * 256 + k0 + k8;
          float4 a0 = *(const float4*)ap;
          float4 a1 = *(const float4*)(ap + 4);
          av[0] = (f16)a0.x; av[1] = (f16)a0.y; av[2] = (f16)a0.z; av[3] = (f16)a0.w;
          av[4] = (f16)a1.x; av[5] = (f16)a1.y; av[6] = (f16)a1.z; av[7] = (f16)a1.w;
        }
      } else {
#pragma unroll
        for (int j = 0; j < 8; ++j) av[j] = (f16)0.f;
      }
      *(f16x8*)&As[row][k8] = av;
    }
    {
      const int n = tid >> 2, k8 = (tid & 3) * 8;
      *(f16x8*)&Bs[n][k8] = *(const f16x8*)(WT + (size_t)(bn + n) * 256 + k0 + k8);
    }
    __syncthreads();
    const f16x8 af0 = *(const f16x8*)&As[wv * 32 + l15][g * 8];
    const f16x8 af1 = *(const f16x8*)&As[wv * 32 + 16 + l15][g * 8];
#pragma unroll
    for (int nt = 0; nt < 4; ++nt) {
      const f16x8 bf = *(const f16x8*)&Bs[nt * 16 + l15][g * 8];
      acc[0][nt] = __builtin_amdgcn_mfma_f32_16x16x32_f16(af0, bf, acc[0][nt], 0, 0, 0);
      acc[1][nt] = __builtin_amdgcn_mfma_f32_16x16x32_f16(af1, bf, acc[1][nt], 0, 0, 0);
    }
    __syncthreads();
  }

  if (mode == 2) {
#pragma unroll
    for (int nt = 0; nt < 4; ++nt) {
      const float bv = bias[bn + nt * 16 + l15];
#pragma unroll
      for (int mt = 0; mt < 2; ++mt)
#pragma unroll
        for (int r = 0; r < 4; ++r)
          Ts[nt * 16 + l15][wv * 32 + mt * 16 + g * 4 + r] = (f16)(acc[mt][nt][r] + bv);
    }
    __syncthreads();
    const int n = tid >> 2, mc = (tid & 3) * 32;
    const int bb = bm >> 12, nk0 = bm & 4095;
    f16* dst = (f16*)C + (size_t)bb * (256 * 4096) +
               (size_t)(bn + n) * 4096 + nk0 + mc;
#pragma unroll
    for (int j = 0; j < 4; ++j)
      *(f16x8*)(dst + j * 8) = *(const f16x8*)&Ts[n][mc + j * 8];
  } else {
#pragma unroll
    for (int nt = 0; nt < 4; ++nt) {
      const int n = bn + nt * 16 + l15;
      const float bv = bias[n];
#pragma unroll
      for (int mt = 0; mt < 2; ++mt)
#pragma unroll
      for (int r = 0; r < 4; ++r) {
        const int m = bm + wv * 32 + mt * 16 + g * 4 + r;
        if (m >= M) continue;
        const float v = acc[mt][nt][r] + bv;
        if (mode == 0) ((float*)C)[(size_t)m * 256 + n] = v;
        else           ((f16*)C)[(size_t)m * 256 + n] = (f16)v;
      }
    }
  }
}

__global__ __launch_bounds__(256) void proj_qkv(
    const float* __restrict__ query, const float* __restrict__ kin,
    const float* __restrict__ vin, const f16* __restrict__ WT,
    const float* __restrict__ bq, const float* __restrict__ bk,
    const float* __restrict__ bv, f16* __restrict__ Qf,
    f16* __restrict__ Kf, f16* __restrict__ Vtf)
{
  const int z = blockIdx.z;
  const int bm = blockIdx.y * 128, bn = blockIdx.x * 64;
  if (z == 0) {
    if (bm >= B_ * NQ_) return;
    gemm_body(query, WT, bq, Qf, B_ * NQ_, 0, 1, bm, bn, threadIdx.x);
  } else if (z == 1) {
    gemm_body(kin, WT + 65536, bk, Kf, B_ * N_, 0, 1, bm, bn, threadIdx.x);
  } else {
    gemm_body(vin, WT + 2 * 65536, bv, Vtf, B_ * N_, 0, 2, bm, bn, threadIdx.x);
  }
}

__global__ __launch_bounds__(256) void gemm_out(
    const f16* __restrict__ X, const f16* __restrict__ WT,
    const float* __restrict__ bp, float* __restrict__ out)
{
  gemm_body(X, WT + 3 * 65536, bp, out, B_ * NQ_, 1, 0,
            blockIdx.y * 128, blockIdx.x * 64, threadIdx.x);
}

// ---------------------------------------------------------------------------
// RPE MLP, fp32 (rpe ~±1500; must not round). Output transposed to
// [b][h][q][j], pre-scaled by log2e.
// ---------------------------------------------------------------------------
__global__ __launch_bounds__(256) void rpe_kernel(
    const float* __restrict__ refpts,
    const float* __restrict__ W1x, const float* __restrict__ b1x, const float* __restrict__ W2x,
    const float* __restrict__ W1y, const float* __restrict__ b1y, const float* __restrict__ W2y,
    float* __restrict__ rpxT, float* __restrict__ rpyT)
{
  __shared__ float sRed[4][64][9];
  const int tid = threadIdx.x;
  const int lane = tid & 63;
  const int wv = __builtin_amdgcn_readfirstlane(tid >> 6);
  const int bq = blockIdx.x;
  const int axis = blockIdx.y;
  const float* W1 = axis ? W1y : W1x;
  const float* b1 = axis ? b1y : b1x;
  const float* W2 = axis ? W2y : W2x;
  float* out = axis ? rpyT : rpxT;
  const int b = bq / NQ_, q = bq % NQ_;

  const float c  = refpts[bq * 4 + axis];
  const float sz = refpts[bq * 4 + 2 + axis];
  const float pos = (lane + 0.5f) * 16.0f;
  const float d0 = c - 0.5f * sz - pos;
  const float d1 = c + 0.5f * sz - pos;
  float acc[8] = {};
  const int r0 = wv * 128;
#pragma unroll 4
  for (int i = 0; i < 128; ++i) {
    const int r = r0 + i;
    const float w10 = W1[r], w11 = W1[512 + r], bb = b1[r];
    const float hv = fmaxf(fmaf(d0, w10, fmaf(d1, w11, bb)), 0.0f);
    const float* w2r = W2 + r * 8;
#pragma unroll
    for (int hh = 0; hh < 8; ++hh) acc[hh] += hv * w2r[hh];
  }
#pragma unroll
  for (int hh = 0; hh < 8; ++hh) sRed[wv][lane][hh] = acc[hh];
  __syncthreads();
  for (int idx = tid; idx < 512; idx += 256) {
    const int hh = idx >> 6, jj = idx & 63;
    out[((size_t)(b * H_ + hh) * NQ_ + q) * 64 + jj] =
        (sRed[0][jj][hh] + sRed[1][jj][hh] + sRed[2][jj][hh] + sRed[3][jj][hh]) * L2E;
  }
}

// ---------------------------------------------------------------------------
// MFMA attention, online softmax (log2 domain), key-split grid.
// Block = (b,h,32q,KH): 8 waves x 256 keys of half KH. Grid 640 — fully
// resident (~2.5 blk/CU, ~33 KB LDS): balance + latency hiding.
// Per 64-key sub-pass: batch-load 4 K-chunks + 8 V-frags + 4 mask-float4,
// QK MFMA (both q-tiles share K), cross-lane max, rescale, exp2 + 4 PV MFMA.
// Block emits fp32 partials (m, l, O) -> attn_merge combines 2 halves.
// ---------------------------------------------------------------------------
__global__ __launch_bounds__(512) void attn_mfma(
    const f16* __restrict__ Qf, const f16* __restrict__ Kf,
    const f16* __restrict__ Vtf, const float* __restrict__ rpxT,
    const float* __restrict__ rpyT, const float* __restrict__ maskf,
    float* __restrict__ pO, float* __restrict__ pml)
{
  __shared__ float srx[32][68];
  __shared__ float sry[32][68];
  __shared__ f16x4 mO4[7][4][64];
  __shared__ float mlm[7][32];
  __shared__ float mll[7][32];

  const int tid = threadIdx.x;
  const int lane = tid & 63;
  const int kw = tid >> 6;
  const int bid = blockIdx.x;
  const int KH = bid & 1;
  const int rest = bid >> 1;
  const int qg = rest % 10;
  const int h  = (rest / 10) % H_;
  const int b  = rest / (10 * H_);
  const int q0 = qg * 32;

  {
    const int qq = tid >> 4, j4 = tid & 15;
    int qa2 = q0 + qq; if (qa2 > NQ_ - 1) qa2 = NQ_ - 1;
    const size_t base = ((size_t)((b * H_ + h) * NQ_ + qa2)) * 64 + j4 * 4;
    *(float4*)&srx[qq][j4 * 4] = *(const float4*)(rpxT + base);
    *(float4*)&sry[qq][j4 * 4] = *(const float4*)(rpyT + base);
  }
  __syncthreads();

  const int l15 = lane & 15, g = lane >> 4;
  const int qrow0 = q0 + l15;
  const int qrow1 = q0 + 16 + l15;
  const int qa = qrow0 > NQ_ - 1 ? NQ_ - 1 : qrow0;
  const int qb = qrow1 > NQ_ - 1 ? NQ_ - 1 : qrow1;

  const f16x8 qf0 = *(const f16x8*)(Qf + (size_t)(b * NQ_ + qa) * 256 + h * 32 + g * 8);
  const f16x8 qf1 = *(const f16x8*)(Qf + (size_t)(b * NQ_ + qb) * 256 + h * 32 + g * 8);

  f32x4 O00 = {0.f,0.f,0.f,0.f}, O01 = {0.f,0.f,0.f,0.f};
  f32x4 O10 = {0.f,0.f,0.f,0.f}, O11 = {0.f,0.f,0.f,0.f};
  float lacc0 = 0.f, lacc1 = 0.f;
  float mrun0 = -1e30f, mrun1 = -1e30f;
  const f16* kb  = Kf + (size_t)b * N_ * 256 + h * 32 + g * 8;
  const f16* v0p = Vtf + (size_t)(b * 256 + h * 32 + l15) * N_ + g * 4;
  const f16* v1p = v0p + (size_t)16 * N_;
  const float* mb = maskf + b * N_;

  for (int sp = 0; sp < 4; ++sp) {
    const int kbase = KH * 2048 + kw * 256 + sp * 64;
    f16x8 kf[4]; f16x4 va[4], vb[4]; float4 m4[4];
#pragma unroll
    for (int cc = 0; cc < 4; ++cc) {
      kf[cc] = *(const f16x8*)(kb + (size_t)(kbase + cc * 16 + l15) * 256);
      va[cc] = *(const f16x4*)(v0p + kbase + cc * 16);
      vb[cc] = *(const f16x4*)(v1p + kbase + cc * 16);
      m4[cc] = *(const float4*)(mb + kbase + cc * 16 + g * 4);
    }
    f32x4 s0[4], s1[4];
    float lm0 = -1e30f, lm1 = -1e30f;
    const float ry0 = sry[l15][kbase >> 6];
    const float ry1 = sry[16 + l15][kbase >> 6];
#pragma unroll
    for (int cc = 0; cc < 4; ++cc) {
      f32x4 S0 = __builtin_amdgcn_mfma_f32_16x16x32_f16(
          kf[cc], qf0, (f32x4){0.f,0.f,0.f,0.f}, 0, 0, 0);
      f32x4 S1 = __builtin_amdgcn_mfma_f32_16x16x32_f16(
          kf[cc], qf1, (f32x4){0.f,0.f,0.f,0.f}, 0, 0, 0);
      const float4 rx0 = *(const float4*)&srx[l15][cc * 16 + g * 4];
      const float4 rx1 = *(const float4*)&srx[16 + l15][cc * 16 + g * 4];
      s0[cc][0] = fmaf(S0[0], L2E, rx0.x + m4[cc].x + ry0);
      s0[cc][1] = fmaf(S0[1], L2E, rx0.y + m4[cc].y + ry0);
      s0[cc][2] = fmaf(S0[2], L2E, rx0.z + m4[cc].z + ry0);
      s0[cc][3] = fmaf(S0[3], L2E, rx0.w + m4[cc].w + ry0);
      s1[cc][0] = fmaf(S1[0], L2E, rx1.x + m4[cc].x + ry1);
      s1[cc][1] = fmaf(S1[1], L2E, rx1.y + m4[cc].y + ry1);
      s1[cc][2] = fmaf(S1[2], L2E, rx1.z + m4[cc].z + ry1);
      s1[cc][3] = fmaf(S1[3], L2E, rx1.w + m4[cc].w + ry1);
      lm0 = fmaxf(lm0, fmaxf(fmaxf(s0[cc][0], s0[cc][1]), fmaxf(s0[cc][2], s0[cc][3])));
      lm1 = fmaxf(lm1, fmaxf(fmaxf(s1[cc][0], s1[cc][1]), fmaxf(s1[cc][2], s1[cc][3])));
    }
    lm0 = fmaxf(lm0, __shfl_xor(lm0, 16));
    lm0 = fmaxf(lm0, __shfl_xor(lm0, 32));
    lm1 = fmaxf(lm1, __shfl_xor(lm1, 16));
    lm1 = fmaxf(lm1, __shfl_xor(lm1, 32));
    const float mn0 = fmaxf(mrun0, lm0);
    const float mn1 = fmaxf(mrun1, lm1);
    const float f0 = exp2f(mrun0 - mn0);
    const float f1 = exp2f(mrun1 - mn1);
    mrun0 = mn0; mrun1 = mn1;
    lacc0 *= f0; lacc1 *= f1;
#pragma unroll
    for (int r = 0; r < 4; ++r) {
      O00[r] *= f0; O01[r] *= f0;
      O10[r] *= f1; O11[r] *= f1;
    }
#pragma unroll
    for (int cc = 0; cc < 4; ++cc) {
      f16x4 pf0, pf1;
#pragma unroll
      for (int r = 0; r < 4; ++r) {
        const float p0 = exp2f(s0[cc][r] - mrun0);
        const float p1 = exp2f(s1[cc][r] - mrun1);
        lacc0 += p0; lacc1 += p1;
        pf0[r] = (f16)p0; pf1[r] = (f16)p1;
      }
      O00 = __builtin_amdgcn_mfma_f32_16x16x16f16(va[cc], pf0, O00, 0, 0, 0);
      O01 = __builtin_amdgcn_mfma_f32_16x16x16f16(vb[cc], pf0, O01, 0, 0, 0);
      O10 = __builtin_amdgcn_mfma_f32_16x16x16f16(va[cc], pf1, O10, 0, 0, 0);
      O11 = __builtin_amdgcn_mfma_f32_16x16x16f16(vb[cc], pf1, O11, 0, 0, 0);
    }
  }

  lacc0 += __shfl_xor(lacc0, 16); lacc0 += __shfl_xor(lacc0, 32);
  lacc1 += __shfl_xor(lacc1, 16); lacc1 += __shfl_xor(lacc1, 32);

  if (kw > 0) {
    f16x4 t;
#pragma unroll
    for (int r = 0; r < 4; ++r) t[r] = (f16)O00[r];
    mO4[kw - 1][0][lane] = t;
#pragma unroll
    for (int r = 0; r < 4; ++r) t[r] = (f16)O01[r];
    mO4[kw - 1][1][lane] = t;
#pragma unroll
    for (int r = 0; r < 4; ++r) t[r] = (f16)O10[r];
    mO4[kw - 1][2][lane] = t;
#pragma unroll
    for (int r = 0; r < 4; ++r) t[r] = (f16)O11[r];
    mO4[kw - 1][3][lane] = t;
    if (lane < 16) {
      mlm[kw - 1][lane]      = mrun0;
      mlm[kw - 1][16 + lane] = mrun1;
      mll[kw - 1][lane]      = lacc0;
      mll[kw - 1][16 + lane] = lacc1;
    }
  }
  __syncthreads();
  if (kw == 0) {
    // qt0 merge
    float ms0 = mrun0, ms1 = mrun1;
#pragma unroll
    for (int w = 0; w < 7; ++w) {
      ms0 = fmaxf(ms0, mlm[w][l15]);
      ms1 = fmaxf(ms1, mlm[w][16 + l15]);
    }
    const float fs0 = exp2f(mrun0 - ms0);
    const float fs1 = exp2f(mrun1 - ms1);
    float lt0 = lacc0 * fs0, lt1 = lacc1 * fs1;
#pragma unroll
    for (int r = 0; r < 4; ++r) {
      O00[r] *= fs0; O01[r] *= fs0;
      O10[r] *= fs1; O11[r] *= fs1;
    }
#pragma unroll
    for (int w = 0; w < 7; ++w) {
      const float fw0 = exp2f(mlm[w][l15] - ms0);
      const float fw1 = exp2f(mlm[w][16 + l15] - ms1);
      lt0 += mll[w][l15] * fw0;
      lt1 += mll[w][16 + l15] * fw1;
#pragma unroll
      for (int r = 0; r < 4; ++r) {
        O00[r] += (float)mO4[w][0][lane][r] * fw0;
        O01[r] += (float)mO4[w][1][lane][r] * fw0;
        O10[r] += (float)mO4[w][2][lane][r] * fw1;
        O11[r] += (float)mO4[w][3][lane][r] * fw1;
      }
    }
    float4* pO4 = (float4*)pO;
    const size_t pb2 = ((size_t)rest * 2 + KH) * 4 * 64;
    pO4[pb2 + 0 * 64 + lane] = make_float4(O00[0], O00[1], O00[2], O00[3]);
    pO4[pb2 + 1 * 64 + lane] = make_float4(O01[0], O01[1], O01[2], O01[3]);
    pO4[pb2 + 2 * 64 + lane] = make_float4(O10[0], O10[1], O10[2], O10[3]);
    pO4[pb2 + 3 * 64 + lane] = make_float4(O11[0], O11[1], O11[2], O11[3]);
    if (lane < 16) {
      float* pp = pml + ((size_t)rest * 2 + KH) * 64;
      pp[l15]      = ms0;
      pp[16 + l15] = lt0;
      pp[32 + l15] = ms1;
      pp[48 + l15] = lt1;
    }
  }
}

// ---------------------------------------------------------------------------
// Merge the two key-half partials per (b,h,32q) and write X (f16).
// ---------------------------------------------------------------------------
__global__ __launch_bounds__(256) void attn_merge(
    const float* __restrict__ pO, const float* __restrict__ pml,
    f16* __restrict__ X)
{
  const int pb = blockIdx.x;
  const int qg = pb % 10;
  const int h  = (pb / 10) % H_;
  const int b  = pb / (10 * H_);
  const int t = threadIdx.x;
  const int qt = t >> 7, oh = (t >> 6) & 1, lane = t & 63;
  const int l15 = lane & 15, g = lane >> 4;

  const float4* pO4 = (const float4*)pO;
  const float4 a = pO4[(((size_t)pb * 2 + 0) * 4 + qt * 2 + oh) * 64 + lane];
  const float4 c = pO4[(((size_t)pb * 2 + 1) * 4 + qt * 2 + oh) * 64 + lane];
  const float* pp0 = pml + ((size_t)pb * 2 + 0) * 64 + qt * 32;
  const float* pp1 = pml + ((size_t)pb * 2 + 1) * 64 + qt * 32;
  const float m0 = pp0[l15], l0 = pp0[16 + l15];
  const float m1 = pp1[l15], l1 = pp1[16 + l15];
  const float ms = fmaxf(m0, m1);
  const float f0 = exp2f(m0 - ms), f1 = exp2f(m1 - ms);
  const float rl = 1.0f / (l0 * f0 + l1 * f1);
  const int qrow = qg * 32 + qt * 16 + l15;
  if (qrow < NQ_) {
    f16x4 o;
    o[0] = (f16)((a.x * f0 + c.x * f1) * rl);
    o[1] = (f16)((a.y * f0 + c.y * f1) * rl);
    o[2] = (f16)((a.z * f0 + c.z * f1) * rl);
    o[3] = (f16)((a.w * f0 + c.w * f1) * rl);
    *(f16x4*)(X + (size_t)(b * NQ_ + qrow) * 256 + h * 32 + oh * 16 + g * 4) = o;
  }
}

// ---------------------------------------------------------------------------
extern "C" void kernel_launch(void* const* d_in, const int* in_sizes, int n_in,
                              void* d_out, int out_size, void* d_ws, size_t ws_size,
                              hipStream_t stream)
{
  const float* query  = (const float*)d_in[0];
  const float* refpts = (const float*)d_in[1];
  const float* kin    = (const float*)d_in[2];
  const float* vin    = (const float*)d_in[3];
  const int*   mask   = (const int*)d_in[5];
  const float* Wq = (const float*)d_in[6];
  const float* bq = (const float*)d_in[7];
  const float* Wk = (const float*)d_in[8];
  const float* bk = (const float*)d_in[9];
  const float* Wv = (const float*)d_in[10];
  const float* bv = (const float*)d_in[11];
  const float* Wp = (const float*)d_in[12];
  const float* bp = (const float*)d_in[13];
  const float* W1x = (const float*)d_in[14];
  const float* b1x = (const float*)d_in[15];
  const float* W2x = (const float*)d_in[16];
  const float* W1y = (const float*)d_in[17];
  const float* b1y = (const float*)d_in[18];
  const float* W2y = (const float*)d_in[19];

  char* wsb = (char*)d_ws;
  f16*   Qf    = (f16*)(wsb);                 // 1280*256 f16   =   655360 B
  f16*   Kf    = (f16*)(wsb + 655360);        // 4*4096*256 f16 =  8388608 B
  f16*   Vtf   = (f16*)(wsb + 9043968);       // 4*256*4096 f16 =  8388608 B
  float* rpxT  = (float*)(wsb + 17432576);    // 4*8*300*64 f32 =  2457600 B
  float* rpyT  = (float*)(wsb + 19890176);    //                   2457600 B
  f16*   X     = (f16*)(wsb + 22347776);      // 1280*256 f16   =   655360 B
  f16*   WT    = (f16*)(wsb + 23003136);      // 4*256*256 f16  =   524288 B
  float* maskf = (float*)(wsb + 23527424);    // 4*4096 f32     =    65536 B
  float* pO    = (float*)(wsb + 23592960);    // 640*4*64*4 f32 =  2621440 B
  float* pml   = (float*)(wsb + 26214400);    // 640*64 f32     =   163840 B

  const float scale = 0.17677669529663687f;  // 32^-0.5

  hipLaunchKernelGGL(prep_wt, dim3(4, 4, 5), dim3(256), 0, stream,
                     Wq, Wk, Wv, Wp, mask, WT, maskf, scale);
  hipLaunchKernelGGL(rpe_kernel, dim3(B_ * NQ_, 2), dim3(256), 0, stream,
                     refpts, W1x, b1x, W2x, W1y, b1y, W2y, rpxT, rpyT);
  hipLaunchKernelGGL(proj_qkv, dim3(4, 128, 3), dim3(256), 0, stream,
                     query, kin, vin, WT, bq, bk, bv, Qf, Kf, Vtf);
  hipLaunchKernelGGL(attn_mfma, dim3(B_ * H_ * 10 * 2), dim3(512), 0, stream,
                     Qf, Kf, Vtf, rpxT, rpyT, maskf, pO, pml);
  hipLaunchKernelGGL(attn_merge, dim3(B_ * H_ * 10), dim3(256), 0, stream,
                     pO, pml, X);
  hipLaunchKernelGGL(gemm_out, dim3(4, 10), dim3(256), 0, stream,
                     X, WT, bp, (float*)d_out);
}